// Round 2
// baseline (3428.766 us; speedup 1.0000x reference)
//
#include <hip/hip_runtime.h>

// Problem constants (fixed by the reference)
#define NN 100000
#define NE 3200000
#define DD 16
constexpr float LAM   = 1.0f;
constexpr float ALP   = 1.0f / (LAM + 1.0f);   // 0.5
constexpr float BETA  = 1.0f - ALP - ALP * LAM; // 0.0 at these constants
constexpr float GAMMA = ALP * LAM;              // 0.5

// ---------------------------------------------------------------------------
// deg[dst] += 1 over all edges (float accumulate; counts <= 2^24 are exact)
__global__ void deg_kernel(const int* __restrict__ dsts, float* __restrict__ deg) {
    int e = blockIdx.x * blockDim.x + threadIdx.x;
    if (e < NE) atomicAdd(&deg[dsts[e]], 1.0f);
}

// ---------------------------------------------------------------------------
// dinv, Z = X*dinv, agg = 0, Y = X.  One thread per float4 (N*4 threads).
__global__ void init_kernel(const float4* __restrict__ X4,
                            const float* __restrict__ deg,
                            float* __restrict__ dinv,
                            float4* __restrict__ Z4,
                            float4* __restrict__ agg4,
                            float4* __restrict__ Y4) {
    int i = blockIdx.x * blockDim.x + threadIdx.x;   // [0, NN*4)
    if (i >= NN * 4) return;
    int node = i >> 2;
    float d  = deg[node];
    float di = (d > 0.5f) ? rsqrtf(d) : 0.0f;
    if ((i & 3) == 0) dinv[node] = di;
    float4 x = X4[i];
    float4 z = make_float4(x.x * di, x.y * di, x.z * di, x.w * di);
    Z4[i]   = z;
    agg4[i] = make_float4(0.f, 0.f, 0.f, 0.f);
    Y4[i]   = x;
}

// ---------------------------------------------------------------------------
// agg[dst*16 + f] += Z[src*16 + f].  4 lanes per edge; each lane does a
// float4 load of Z and 4 f32 atomics to consecutive addresses.
__global__ void scatter_kernel(const int* __restrict__ srcs,
                               const int* __restrict__ dsts,
                               const float4* __restrict__ Z4,
                               float* __restrict__ agg) {
    int g = blockIdx.x * blockDim.x + threadIdx.x;   // [0, NE*4) exactly
    int e = g >> 2;
    int q = g & 3;
    int s = srcs[e];
    int d = dsts[e];
    float4 z = Z4[s * 4 + q];
    float* a = agg + d * DD + q * 4;
    atomicAdd(a + 0, z.x);
    atomicAdd(a + 1, z.y);
    atomicAdd(a + 2, z.z);
    atomicAdd(a + 3, z.w);
}

// ---------------------------------------------------------------------------
// Y = clip(BETA*Y + GAMMA*agg*dinv + ALP*X); Y[mask]=X; Z = Y*dinv; agg = 0.
__global__ void combine_kernel(const float4* __restrict__ X4,
                               const int* __restrict__ mask,   // int32 bool
                               const float* __restrict__ dinv,
                               float4* __restrict__ agg4,
                               float4* __restrict__ Y4,
                               float4* __restrict__ Z4) {
    int i = blockIdx.x * blockDim.x + threadIdx.x;   // [0, NN*4)
    if (i >= NN * 4) return;
    int node = i >> 2;
    float di = dinv[node];
    float4 a = agg4[i];
    float4 x = X4[i];
    float4 v;
    v.x = GAMMA * a.x * di + ALP * x.x;
    v.y = GAMMA * a.y * di + ALP * x.y;
    v.z = GAMMA * a.z * di + ALP * x.z;
    v.w = GAMMA * a.w * di + ALP * x.w;
    if (BETA != 0.0f) {           // compile-time dead at these constants
        float4 y = Y4[i];
        v.x += BETA * y.x; v.y += BETA * y.y; v.z += BETA * y.z; v.w += BETA * y.w;
    }
    v.x = fminf(fmaxf(v.x, -1.0f), 1.0f);
    v.y = fminf(fmaxf(v.y, -1.0f), 1.0f);
    v.z = fminf(fmaxf(v.z, -1.0f), 1.0f);
    v.w = fminf(fmaxf(v.w, -1.0f), 1.0f);
    if (mask[node] != 0) v = x;   // masked rows carry (unclipped) X
    Y4[i]   = v;
    Z4[i]   = make_float4(v.x * di, v.y * di, v.z * di, v.w * di);
    agg4[i] = make_float4(0.f, 0.f, 0.f, 0.f);   // fused re-zero for next iter
}

// ---------------------------------------------------------------------------
extern "C" void kernel_launch(void* const* d_in, const int* in_sizes, int n_in,
                              void* d_out, int out_size, void* d_ws, size_t ws_size,
                              hipStream_t stream) {
    const int*   edge_index = (const int*)d_in[0];   // (2, E) int32
    const float* X          = (const float*)d_in[1]; // (N, 16) f32
    const int*   mask       = (const int*)d_in[2];   // (N,) bool as int32

    const int* srcs = edge_index;        // row 0
    const int* dsts = edge_index + NE;   // row 1

    float* Y = (float*)d_out;            // (N, 16)

    // workspace layout
    float* deg  = (float*)d_ws;          // NN floats
    float* dinv = deg  + NN;             // NN floats
    float* Z    = dinv + NN;             // NN*DD floats
    float* agg  = Z    + NN * DD;        // NN*DD floats
    // total: (2*NN + 2*NN*DD)*4 = 13.6 MB

    hipMemsetAsync(deg, 0, NN * sizeof(float), stream);

    deg_kernel<<<(NE + 255) / 256, 256, 0, stream>>>(dsts, deg);

    init_kernel<<<(NN * 4 + 255) / 256, 256, 0, stream>>>(
        (const float4*)X, deg, dinv, (float4*)Z, (float4*)agg, (float4*)Y);

    for (int t = 0; t < 5; ++t) {
        scatter_kernel<<<(NE * 4) / 256, 256, 0, stream>>>(
            srcs, dsts, (const float4*)Z, agg);
        combine_kernel<<<(NN * 4 + 255) / 256, 256, 0, stream>>>(
            (const float4*)X, mask, dinv, (float4*)agg, (float4*)Y, (float4*)Z);
    }
}

// Round 3
// 730.124 us; speedup vs baseline: 4.6961x; 4.6961x over previous
//
#include <hip/hip_runtime.h>

// Problem constants (fixed by the reference)
#define NN 100000
#define NE 3200000
#define DD 16
constexpr float LAM   = 1.0f;
constexpr float ALP   = 1.0f / (LAM + 1.0f);   // 0.5
constexpr float GAMMA = ALP * LAM;              // 0.5
// (1 - ALP - ALP*LAM) == 0 at these constants -> no Y carry term

// ---------------------------------------------------------------------------
// Integer degree histogram over dst.
__global__ void hist_kernel(const int* __restrict__ dsts, int* __restrict__ deg) {
    int e = blockIdx.x * blockDim.x + threadIdx.x;
    if (e < NE) atomicAdd(&deg[dsts[e]], 1);
}

// ---------------------------------------------------------------------------
// Per node: dinv; CSR segment start via atomic bump of a global cursor.
// Segment ordering across nodes is arbitrary — only contiguity matters.
__global__ void offsets_kernel(const int* __restrict__ deg,
                               float* __restrict__ dinv,
                               int* __restrict__ row_start,
                               int* __restrict__ cursor,
                               int* __restrict__ total) {
    int n = blockIdx.x * blockDim.x + threadIdx.x;
    if (n >= NN) return;
    int d = deg[n];
    dinv[n] = (d > 0) ? rsqrtf((float)d) : 0.0f;
    int s = atomicAdd(total, d);
    row_start[n] = s;
    cursor[n]    = s;
}

// ---------------------------------------------------------------------------
// Bucket fill: csr_src[segment(dst)] <- src  (order within segment arbitrary)
__global__ void fill_kernel(const int* __restrict__ srcs,
                            const int* __restrict__ dsts,
                            int* __restrict__ cursor,
                            int* __restrict__ csr_src) {
    int e = blockIdx.x * blockDim.x + threadIdx.x;
    if (e >= NE) return;
    int pos = atomicAdd(&cursor[dsts[e]], 1);
    csr_src[pos] = srcs[e];
}

// ---------------------------------------------------------------------------
// Z0 = X * dinv   (one thread per float4)
__global__ void zinit_kernel(const float4* __restrict__ X4,
                             const float* __restrict__ dinv,
                             float4* __restrict__ Z4) {
    int i = blockIdx.x * blockDim.x + threadIdx.x;   // [0, NN*4)
    if (i >= NN * 4) return;
    float di = dinv[i >> 2];
    float4 x = X4[i];
    Z4[i] = make_float4(x.x * di, x.y * di, x.z * di, x.w * di);
}

// ---------------------------------------------------------------------------
// Fused gather + combine. 16 lanes per node; lane f owns feature f.
// acc = sum_{s in N(node)} Zin[s][f]; v = clip(GAMMA*acc*dinv + ALP*X); mask;
// last ? Y = v : Zout = v*dinv.  Atomic-free.
__global__ void gather_kernel(const int* __restrict__ csr_src,
                              const int* __restrict__ row_start,
                              const int* __restrict__ deg,
                              const float* __restrict__ dinv,
                              const float* __restrict__ X,
                              const int* __restrict__ mask,
                              const float* __restrict__ Zin,
                              float* __restrict__ Zout,
                              float* __restrict__ Y,
                              int last) {
    int tid  = blockIdx.x * blockDim.x + threadIdx.x;  // NN*16 exactly
    int node = tid >> 4;
    int f    = tid & 15;
    if (node >= NN) return;

    int start = row_start[node];
    int d     = deg[node];

    float acc = 0.0f;
    int i = 0;
    // Full 16-neighbor chunks: one coalesced csr load per chunk, then 16
    // independent 64B-coalesced Z-row loads (good MLP).
    while (d - i >= 16) {
        int sv = csr_src[start + i + f];
        #pragma unroll
        for (int j = 0; j < 16; ++j) {
            int s = __shfl(sv, j, 16);
            acc += Zin[s * DD + f];
        }
        i += 16;
    }
    int rem = d - i;
    if (rem > 0) {
        int sv = (f < rem) ? csr_src[start + i + f] : 0;
        for (int j = 0; j < rem; ++j) {
            int s = __shfl(sv, j, 16);
            acc += Zin[s * DD + f];
        }
    }

    float di = dinv[node];
    float x  = X[node * DD + f];
    float v  = GAMMA * acc * di + ALP * x;
    v = fminf(fmaxf(v, -1.0f), 1.0f);
    if (mask[node] != 0) v = x;
    if (last) Y[node * DD + f]    = v;
    else      Zout[node * DD + f] = v * di;
}

// ---------------------------------------------------------------------------
extern "C" void kernel_launch(void* const* d_in, const int* in_sizes, int n_in,
                              void* d_out, int out_size, void* d_ws, size_t ws_size,
                              hipStream_t stream) {
    const int*   edge_index = (const int*)d_in[0];   // (2, E) int32
    const float* X          = (const float*)d_in[1]; // (N, 16) f32
    const int*   mask       = (const int*)d_in[2];   // (N,) bool as int32

    const int* srcs = edge_index;        // row 0
    const int* dsts = edge_index + NE;   // row 1

    float* Y = (float*)d_out;            // (N, 16); also used as Z scratch

    // workspace layout (ints first so one memset covers deg+total)
    int*   deg       = (int*)d_ws;           // NN
    int*   total     = deg + NN;             // 1
    int*   row_start = total + 1;            // NN
    int*   cursor    = row_start + NN;       // NN
    int*   csr_src   = cursor + NN;          // NE
    float* dinv      = (float*)(csr_src + NE);       // NN
    float* Za        = dinv + NN;                    // NN*DD
    // total ws bytes: (3*NN+1+NE)*4 + (NN + NN*DD)*4 ≈ 20.8 MB
    float* Zb        = Y;   // d_out doubles as the second Z buffer

    hipMemsetAsync(deg, 0, (NN + 1) * sizeof(int), stream);  // deg + total

    hist_kernel<<<(NE + 255) / 256, 256, 0, stream>>>(dsts, deg);
    offsets_kernel<<<(NN + 255) / 256, 256, 0, stream>>>(deg, dinv, row_start, cursor, total);
    fill_kernel<<<(NE + 255) / 256, 256, 0, stream>>>(srcs, dsts, cursor, csr_src);
    zinit_kernel<<<(NN * 4 + 255) / 256, 256, 0, stream>>>((const float4*)X, dinv, (float4*)Za);

    // Z ping-pong: Za -> Zb -> Za -> Zb -> Za -> Y(last)
    const float* zin  = Za;
    float*       zout = Zb;
    for (int t = 0; t < 5; ++t) {
        int last = (t == 4);
        gather_kernel<<<(NN * 16) / 256, 256, 0, stream>>>(
            csr_src, row_start, deg, dinv, X, mask, zin, zout, Y, last);
        const float* tmp = zout;
        zout = (float*)zin;
        zin  = tmp;
    }
}

// Round 4
// 352.009 us; speedup vs baseline: 9.7406x; 2.0742x over previous
//
#include <hip/hip_runtime.h>

// Problem constants (fixed by the reference)
#define NN 100000
#define NE 3200000
#define DD 16
#define NB 782              // ceil(NN / 128) coarse buckets (128 dsts each)
#define NBP 1024            // padded bucket count (pow2 for scans)
#define CHUNK 8192          // edges per bucket_scatter block
#define NCHUNK ((NE + CHUNK - 1) / CHUNK)   // 391
#define BCAP 8192           // max edges per coarse bucket (Poisson(4096), 64 sigma)

constexpr float LAM   = 1.0f;
constexpr float ALP   = 1.0f / (LAM + 1.0f);   // 0.5
constexpr float GAMMA = ALP * LAM;             // 0.5
// (1 - ALP - ALP*LAM) == 0 at these constants -> no Y carry term

// ---------------------------------------------------------------------------
// Coarse histogram over dst>>7, LDS-aggregated.
__global__ void bucket_hist(const int* __restrict__ dsts, int* __restrict__ bcount) {
    __shared__ int lh[NBP];
    for (int t = threadIdx.x; t < NBP; t += blockDim.x) lh[t] = 0;
    __syncthreads();
    int stride = gridDim.x * blockDim.x;
    for (int e = blockIdx.x * blockDim.x + threadIdx.x; e < NE; e += stride)
        atomicAdd(&lh[dsts[e] >> 7], 1);
    __syncthreads();
    for (int t = threadIdx.x; t < NB; t += blockDim.x) {
        int c = lh[t];
        if (c) atomicAdd(&bcount[t], c);
    }
}

// ---------------------------------------------------------------------------
// Exclusive prefix over bucket counts -> bases + cursors. One block, 1024 thr.
__global__ void bucket_scan(const int* __restrict__ bcount,
                            int* __restrict__ bbase, int* __restrict__ bcursor) {
    __shared__ int sc[NBP];
    int t = threadIdx.x;
    sc[t] = (t < NB) ? bcount[t] : 0;
    __syncthreads();
    for (int s = 1; s < NBP; s <<= 1) {
        int v = (t >= s) ? sc[t - s] : 0;
        __syncthreads();
        sc[t] += v;
        __syncthreads();
    }
    int excl = (t == 0) ? 0 : sc[t - 1];
    if (t < NB) { bbase[t] = excl; bcursor[t] = excl; }
}

// ---------------------------------------------------------------------------
// Counting-sort each CHUNK of edges by coarse bucket in LDS, then flush packed
// ((dst&127)<<17)|src words to per-bucket global runs (coalesced-ish).
__global__ __launch_bounds__(NBP) void bucket_scatter(
        const int* __restrict__ srcs, const int* __restrict__ dsts,
        int* __restrict__ bcursor, unsigned int* __restrict__ pk) {
    __shared__ int lh[NBP];                 // per-chunk bucket counts
    __shared__ int off[NBP];                // exclusive offsets -> cursors
    __shared__ int gb[NBP];                 // global_run_base - local_excl
    __shared__ unsigned int ssrc[CHUNK];
    __shared__ unsigned int sdst[CHUNK];
    int t = threadIdx.x;                    // 1024 threads
    int base = blockIdx.x * CHUNK;
    int n = NE - base; if (n > CHUNK) n = CHUNK;

    lh[t] = 0;
    __syncthreads();
    for (int i = t; i < n; i += NBP)
        atomicAdd(&lh[dsts[base + i] >> 7], 1);
    __syncthreads();
    off[t] = lh[t];
    __syncthreads();
    for (int s = 1; s < NBP; s <<= 1) {     // inclusive scan
        int v = (t >= s) ? off[t - s] : 0;
        __syncthreads();
        off[t] += v;
        __syncthreads();
    }
    int cnt  = lh[t];
    int excl = off[t] - cnt;                // own-index only: no sync needed
    off[t] = excl;                          // becomes the LDS scatter cursor
    if (cnt > 0) gb[t] = atomicAdd(&bcursor[t], cnt) - excl;
    __syncthreads();
    for (int i = t; i < n; i += NBP) {
        int d = dsts[base + i];
        int s = srcs[base + i];
        int p = atomicAdd(&off[d >> 7], 1);
        ssrc[p] = (unsigned int)s;
        sdst[p] = (unsigned int)d;
    }
    __syncthreads();
    for (int p = t; p < n; p += NBP) {
        unsigned int d = sdst[p];
        int b = d >> 7;
        pk[gb[b] + p] = ((d & 127u) << 17) | ssrc[p];
    }
}

// ---------------------------------------------------------------------------
// One block per coarse bucket: exact deg/row_start/dinv for its 128 dsts and
// fully-sorted csr_src flushed coalesced. csr_src may alias pk_in (each block
// reads its own range completely before overwriting it).
__global__ void fine_csr(const unsigned int* __restrict__ pk_in,
                         int* __restrict__ csr_src,
                         const int* __restrict__ bbase, const int* __restrict__ bcount,
                         int* __restrict__ deg, int* __restrict__ row_start,
                         float* __restrict__ dinv) {
    __shared__ int lh[128], off[128];
    __shared__ int sbuf[BCAP];
    int b  = blockIdx.x;
    int t  = threadIdx.x;                   // 256 threads
    int b0 = bbase[b];
    int cnt = bcount[b];
    if (t < 128) lh[t] = 0;
    __syncthreads();
    for (int i = t; i < cnt; i += 256)
        atomicAdd(&lh[pk_in[b0 + i] >> 17], 1);
    __syncthreads();
    if (t < 128) off[t] = lh[t];
    __syncthreads();
    for (int s = 1; s < 128; s <<= 1) {     // inclusive scan over 128
        int v = (t >= s && t < 128) ? off[t - s] : 0;
        __syncthreads();
        if (t < 128) off[t] += v;
        __syncthreads();
    }
    if (t < 128) {
        int c    = lh[t];
        int excl = off[t] - c;
        int dst  = (b << 7) + t;
        if (dst < NN) {
            deg[dst]       = c;
            row_start[dst] = b0 + excl;
            dinv[dst]      = (c > 0) ? rsqrtf((float)c) : 0.0f;
        }
        off[t] = excl;                      // scatter cursor
    }
    __syncthreads();
    for (int i = t; i < cnt; i += 256) {
        unsigned int v = pk_in[b0 + i];
        int p = atomicAdd(&off[v >> 17], 1);
        sbuf[p] = (int)(v & 0x1FFFFu);
    }
    __syncthreads();
    for (int i = t; i < cnt; i += 256)
        csr_src[b0 + i] = sbuf[i];
}

// ---------------------------------------------------------------------------
// Z0 = X * dinv   (one thread per float4)
__global__ void zinit_kernel(const float4* __restrict__ X4,
                             const float* __restrict__ dinv,
                             float4* __restrict__ Z4) {
    int i = blockIdx.x * blockDim.x + threadIdx.x;   // [0, NN*4)
    if (i >= NN * 4) return;
    float di = dinv[i >> 2];
    float4 x = X4[i];
    Z4[i] = make_float4(x.x * di, x.y * di, x.z * di, x.w * di);
}

// ---------------------------------------------------------------------------
// Fused gather + combine (unchanged from the passing round). 16 lanes/node.
__global__ void gather_kernel(const int* __restrict__ csr_src,
                              const int* __restrict__ row_start,
                              const int* __restrict__ deg,
                              const float* __restrict__ dinv,
                              const float* __restrict__ X,
                              const int* __restrict__ mask,
                              const float* __restrict__ Zin,
                              float* __restrict__ Zout,
                              float* __restrict__ Y,
                              int last) {
    int tid  = blockIdx.x * blockDim.x + threadIdx.x;  // NN*16 exactly
    int node = tid >> 4;
    int f    = tid & 15;
    if (node >= NN) return;

    int start = row_start[node];
    int d     = deg[node];

    float acc = 0.0f;
    int i = 0;
    while (d - i >= 16) {
        int sv = csr_src[start + i + f];
        #pragma unroll
        for (int j = 0; j < 16; ++j) {
            int s = __shfl(sv, j, 16);
            acc += Zin[s * DD + f];
        }
        i += 16;
    }
    int rem = d - i;
    if (rem > 0) {
        int sv = (f < rem) ? csr_src[start + i + f] : 0;
        for (int j = 0; j < rem; ++j) {
            int s = __shfl(sv, j, 16);
            acc += Zin[s * DD + f];
        }
    }

    float di = dinv[node];
    float x  = X[node * DD + f];
    float v  = GAMMA * acc * di + ALP * x;
    v = fminf(fmaxf(v, -1.0f), 1.0f);
    if (mask[node] != 0) v = x;
    if (last) Y[node * DD + f]    = v;
    else      Zout[node * DD + f] = v * di;
}

// ---------------------------------------------------------------------------
extern "C" void kernel_launch(void* const* d_in, const int* in_sizes, int n_in,
                              void* d_out, int out_size, void* d_ws, size_t ws_size,
                              hipStream_t stream) {
    const int*   edge_index = (const int*)d_in[0];   // (2, E) int32
    const float* X          = (const float*)d_in[1]; // (N, 16) f32
    const int*   mask       = (const int*)d_in[2];   // (N,) bool as int32

    const int* srcs = edge_index;        // row 0
    const int* dsts = edge_index + NE;   // row 1

    float* Y = (float*)d_out;            // (N, 16); also used as Z scratch

    // workspace layout (~20.8 MB)
    int*   bcount    = (int*)d_ws;               // NBP
    int*   bbase     = bcount + NBP;             // NBP
    int*   bcursor   = bbase + NBP;              // NBP
    int*   deg       = bcursor + NBP;            // NN
    int*   row_start = deg + NN;                 // NN
    float* dinv      = (float*)(row_start + NN); // NN
    unsigned int* pk = (unsigned int*)(dinv + NN);   // NE (csr_src aliases this)
    float* Za        = (float*)(pk + NE);        // NN*DD
    float* Zb        = Y;                        // d_out doubles as 2nd Z buffer
    int*   csr_src   = (int*)pk;

    hipMemsetAsync(bcount, 0, NBP * sizeof(int), stream);

    bucket_hist<<<512, 256, 0, stream>>>(dsts, bcount);
    bucket_scan<<<1, NBP, 0, stream>>>(bcount, bbase, bcursor);
    bucket_scatter<<<NCHUNK, NBP, 0, stream>>>(srcs, dsts, bcursor, pk);
    fine_csr<<<NB, 256, 0, stream>>>(pk, csr_src, bbase, bcount, deg, row_start, dinv);
    zinit_kernel<<<(NN * 4 + 255) / 256, 256, 0, stream>>>((const float4*)X, dinv, (float4*)Za);

    // Z ping-pong: Za -> Zb -> Za -> Zb -> Za -> Y(last)
    const float* zin  = Za;
    float*       zout = Zb;
    for (int t = 0; t < 5; ++t) {
        int last = (t == 4);
        gather_kernel<<<(NN * 16) / 256, 256, 0, stream>>>(
            csr_src, row_start, deg, dinv, X, mask, zin, zout, Y, last);
        const float* tmp = zout;
        zout = (float*)zin;
        zin  = tmp;
    }
}

// Round 5
// 350.784 us; speedup vs baseline: 9.7746x; 1.0035x over previous
//
#include <hip/hip_runtime.h>

// Problem constants (fixed by the reference)
#define NN 100000
#define NE 3200000
#define DD 16
#define NB 782              // ceil(NN / 128) coarse buckets (128 dsts each)
#define NBP 1024            // padded bucket count (pow2 for scans)
#define CHUNK 8192          // edges per bucket_scatter block
#define NCHUNK ((NE + CHUNK - 1) / CHUNK)   // 391
#define BCAP 8192           // max edges per coarse bucket (Poisson(4096), 64 sigma)

constexpr float LAM   = 1.0f;
constexpr float ALP   = 1.0f / (LAM + 1.0f);   // 0.5
constexpr float GAMMA = ALP * LAM;             // 0.5
// (1 - ALP - ALP*LAM) == 0 at these constants -> no Y carry term

// bf16 helpers: RTNE pack, cheap unpack
static __device__ inline unsigned short f2bf(float f) {
    unsigned int u = __float_as_uint(f);
    u = (u + 0x7FFFu + ((u >> 16) & 1u)) >> 16;
    return (unsigned short)u;
}
static __device__ inline float bf2f(unsigned short b) {
    return __uint_as_float(((unsigned int)b) << 16);
}

// ---------------------------------------------------------------------------
// Coarse histogram over dst>>7, LDS-aggregated.
__global__ void bucket_hist(const int* __restrict__ dsts, int* __restrict__ bcount) {
    __shared__ int lh[NBP];
    for (int t = threadIdx.x; t < NBP; t += blockDim.x) lh[t] = 0;
    __syncthreads();
    int stride = gridDim.x * blockDim.x;
    for (int e = blockIdx.x * blockDim.x + threadIdx.x; e < NE; e += stride)
        atomicAdd(&lh[dsts[e] >> 7], 1);
    __syncthreads();
    for (int t = threadIdx.x; t < NB; t += blockDim.x) {
        int c = lh[t];
        if (c) atomicAdd(&bcount[t], c);
    }
}

// ---------------------------------------------------------------------------
// Exclusive prefix over bucket counts -> bases + cursors. One block, 1024 thr.
__global__ void bucket_scan(const int* __restrict__ bcount,
                            int* __restrict__ bbase, int* __restrict__ bcursor) {
    __shared__ int sc[NBP];
    int t = threadIdx.x;
    sc[t] = (t < NB) ? bcount[t] : 0;
    __syncthreads();
    for (int s = 1; s < NBP; s <<= 1) {
        int v = (t >= s) ? sc[t - s] : 0;
        __syncthreads();
        sc[t] += v;
        __syncthreads();
    }
    int excl = (t == 0) ? 0 : sc[t - 1];
    if (t < NB) { bbase[t] = excl; bcursor[t] = excl; }
}

// ---------------------------------------------------------------------------
// Counting-sort each CHUNK of edges by coarse bucket in LDS, then flush packed
// ((dst&127)<<17)|src words to per-bucket global runs (coalesced-ish).
__global__ __launch_bounds__(NBP) void bucket_scatter(
        const int* __restrict__ srcs, const int* __restrict__ dsts,
        int* __restrict__ bcursor, unsigned int* __restrict__ pk) {
    __shared__ int lh[NBP];                 // per-chunk bucket counts
    __shared__ int off[NBP];                // exclusive offsets -> cursors
    __shared__ int gb[NBP];                 // global_run_base - local_excl
    __shared__ unsigned int ssrc[CHUNK];
    __shared__ unsigned int sdst[CHUNK];
    int t = threadIdx.x;                    // 1024 threads
    int base = blockIdx.x * CHUNK;
    int n = NE - base; if (n > CHUNK) n = CHUNK;

    lh[t] = 0;
    __syncthreads();
    for (int i = t; i < n; i += NBP)
        atomicAdd(&lh[dsts[base + i] >> 7], 1);
    __syncthreads();
    off[t] = lh[t];
    __syncthreads();
    for (int s = 1; s < NBP; s <<= 1) {     // inclusive scan
        int v = (t >= s) ? off[t - s] : 0;
        __syncthreads();
        off[t] += v;
        __syncthreads();
    }
    int cnt  = lh[t];
    int excl = off[t] - cnt;                // own-index only: no sync needed
    off[t] = excl;                          // becomes the LDS scatter cursor
    if (cnt > 0) gb[t] = atomicAdd(&bcursor[t], cnt) - excl;
    __syncthreads();
    for (int i = t; i < n; i += NBP) {
        int d = dsts[base + i];
        int s = srcs[base + i];
        int p = atomicAdd(&off[d >> 7], 1);
        ssrc[p] = (unsigned int)s;
        sdst[p] = (unsigned int)d;
    }
    __syncthreads();
    for (int p = t; p < n; p += NBP) {
        unsigned int d = sdst[p];
        int b = d >> 7;
        pk[gb[b] + p] = ((d & 127u) << 17) | ssrc[p];
    }
}

// ---------------------------------------------------------------------------
// One block per coarse bucket: exact deg/row_start/dinv for its 128 dsts and
// fully-sorted csr_src flushed coalesced. csr_src may alias pk_in (each block
// reads its own range completely before overwriting it).
__global__ void fine_csr(const unsigned int* __restrict__ pk_in,
                         int* __restrict__ csr_src,
                         const int* __restrict__ bbase, const int* __restrict__ bcount,
                         int* __restrict__ deg, int* __restrict__ row_start,
                         float* __restrict__ dinv) {
    __shared__ int lh[128], off[128];
    __shared__ int sbuf[BCAP];
    int b  = blockIdx.x;
    int t  = threadIdx.x;                   // 256 threads
    int b0 = bbase[b];
    int cnt = bcount[b];
    if (t < 128) lh[t] = 0;
    __syncthreads();
    for (int i = t; i < cnt; i += 256)
        atomicAdd(&lh[pk_in[b0 + i] >> 17], 1);
    __syncthreads();
    if (t < 128) off[t] = lh[t];
    __syncthreads();
    for (int s = 1; s < 128; s <<= 1) {     // inclusive scan over 128
        int v = (t >= s && t < 128) ? off[t - s] : 0;
        __syncthreads();
        if (t < 128) off[t] += v;
        __syncthreads();
    }
    if (t < 128) {
        int c    = lh[t];
        int excl = off[t] - c;
        int dst  = (b << 7) + t;
        if (dst < NN) {
            deg[dst]       = c;
            row_start[dst] = b0 + excl;
            dinv[dst]      = (c > 0) ? rsqrtf((float)c) : 0.0f;
        }
        off[t] = excl;                      // scatter cursor
    }
    __syncthreads();
    for (int i = t; i < cnt; i += 256) {
        unsigned int v = pk_in[b0 + i];
        int p = atomicAdd(&off[v >> 17], 1);
        sbuf[p] = (int)(v & 0x1FFFFu);
    }
    __syncthreads();
    for (int i = t; i < cnt; i += 256)
        csr_src[b0 + i] = sbuf[i];
}

// ---------------------------------------------------------------------------
// Z0 = bf16(X * dinv)   (one thread per element)
__global__ void zinit_kernel(const float* __restrict__ X,
                             const float* __restrict__ dinv,
                             unsigned short* __restrict__ Z) {
    int i = blockIdx.x * blockDim.x + threadIdx.x;   // [0, NN*DD)
    if (i >= NN * DD) return;
    Z[i] = f2bf(X[i] * dinv[i >> 4]);
}

// ---------------------------------------------------------------------------
// Fused gather + combine. 16 lanes per node; lane f owns feature f.
// Z is bf16 (3.2 MB table -> per-XCD L2 resident); accumulate in f32.
// Streams (csr/X/mask) use nontemporal loads to avoid evicting Z from L2.
__global__ void gather_kernel(const int* __restrict__ csr_src,
                              const int* __restrict__ row_start,
                              const int* __restrict__ deg,
                              const float* __restrict__ dinv,
                              const float* __restrict__ X,
                              const int* __restrict__ mask,
                              const unsigned short* __restrict__ Zin,
                              unsigned short* __restrict__ Zout,
                              float* __restrict__ Y,
                              int last) {
    int tid  = blockIdx.x * blockDim.x + threadIdx.x;  // NN*16 exactly
    int node = tid >> 4;
    int f    = tid & 15;
    if (node >= NN) return;

    int start = row_start[node];
    int d     = deg[node];

    float acc = 0.0f;
    int i = 0;
    // Full 16-neighbor chunks: one coalesced csr load per chunk, then 16
    // independent 2B gathers per lane (4 cache lines per wave instr).
    while (d - i >= 16) {
        int sv = __builtin_nontemporal_load(&csr_src[start + i + f]);
        #pragma unroll
        for (int j = 0; j < 16; ++j) {
            int s = __shfl(sv, j, 16);
            acc += bf2f(Zin[s * DD + f]);
        }
        i += 16;
    }
    int rem = d - i;
    if (rem > 0) {
        int sv = (f < rem) ? __builtin_nontemporal_load(&csr_src[start + i + f]) : 0;
        for (int j = 0; j < rem; ++j) {
            int s = __shfl(sv, j, 16);
            acc += bf2f(Zin[s * DD + f]);
        }
    }

    float di = dinv[node];
    float x  = __builtin_nontemporal_load(&X[node * DD + f]);
    float v  = GAMMA * acc * di + ALP * x;
    v = fminf(fmaxf(v, -1.0f), 1.0f);
    if (__builtin_nontemporal_load(&mask[node]) != 0) v = x;
    if (last) Y[node * DD + f]    = v;
    else      Zout[node * DD + f] = f2bf(v * di);
}

// ---------------------------------------------------------------------------
extern "C" void kernel_launch(void* const* d_in, const int* in_sizes, int n_in,
                              void* d_out, int out_size, void* d_ws, size_t ws_size,
                              hipStream_t stream) {
    const int*   edge_index = (const int*)d_in[0];   // (2, E) int32
    const float* X          = (const float*)d_in[1]; // (N, 16) f32
    const int*   mask       = (const int*)d_in[2];   // (N,) bool as int32

    const int* srcs = edge_index;        // row 0
    const int* dsts = edge_index + NE;   // row 1

    float* Y = (float*)d_out;            // (N, 16) f32 output

    // workspace layout (~21 MB)
    int*   bcount    = (int*)d_ws;               // NBP
    int*   bbase     = bcount + NBP;             // NBP
    int*   bcursor   = bbase + NBP;              // NBP
    int*   deg       = bcursor + NBP;            // NN
    int*   row_start = deg + NN;                 // NN
    float* dinv      = (float*)(row_start + NN); // NN
    unsigned int* pk = (unsigned int*)(dinv + NN);   // NE (csr_src aliases this)
    unsigned short* Za = (unsigned short*)(pk + NE); // NN*DD bf16
    unsigned short* Zb = Za + NN * DD;               // NN*DD bf16
    int*   csr_src   = (int*)pk;

    hipMemsetAsync(bcount, 0, NBP * sizeof(int), stream);

    bucket_hist<<<512, 256, 0, stream>>>(dsts, bcount);
    bucket_scan<<<1, NBP, 0, stream>>>(bcount, bbase, bcursor);
    bucket_scatter<<<NCHUNK, NBP, 0, stream>>>(srcs, dsts, bcursor, pk);
    fine_csr<<<NB, 256, 0, stream>>>(pk, csr_src, bbase, bcount, deg, row_start, dinv);
    zinit_kernel<<<(NN * DD + 255) / 256, 256, 0, stream>>>(X, dinv, Za);

    // Z ping-pong: Za -> Zb -> Za -> Zb -> Za -> Y(last)
    const unsigned short* zin  = Za;
    unsigned short*       zout = Zb;
    for (int t = 0; t < 5; ++t) {
        int last = (t == 4);
        gather_kernel<<<(NN * 16) / 256, 256, 0, stream>>>(
            csr_src, row_start, deg, dinv, X, mask, zin, zout, Y, last);
        const unsigned short* tmp = zout;
        zout = (unsigned short*)zin;
        zin  = tmp;
    }
}

// Round 6
// 286.196 us; speedup vs baseline: 11.9805x; 1.2257x over previous
//
#include <hip/hip_runtime.h>

// Problem constants (fixed by the reference)
#define NN 100000
#define NE 3200000
#define DD 16
#define NB 782              // ceil(NN / 128) coarse buckets (128 dsts each)
#define NBP 1024            // padded bucket count (pow2 for scans)
#define CHUNK 8192          // edges per bucket_scatter block
#define NCHUNK ((NE + CHUNK - 1) / CHUNK)   // 391
#define BCAP 8192           // max edges per coarse bucket (Poisson(4096), 64 sigma)

constexpr float LAM   = 1.0f;
constexpr float ALP   = 1.0f / (LAM + 1.0f);   // 0.5
constexpr float GAMMA = ALP * LAM;             // 0.5
// (1 - ALP - ALP*LAM) == 0 at these constants -> no Y carry term

// bf16 helpers: RTNE pack, cheap unpack
static __device__ inline unsigned short f2bf(float f) {
    unsigned int u = __float_as_uint(f);
    u = (u + 0x7FFFu + ((u >> 16) & 1u)) >> 16;
    return (unsigned short)u;
}
static __device__ inline float bf2f(unsigned short b) {
    return __uint_as_float(((unsigned int)b) << 16);
}

// ---------------------------------------------------------------------------
// Coarse histogram over dst>>7, LDS-aggregated.
__global__ void bucket_hist(const int* __restrict__ dsts, int* __restrict__ bcount) {
    __shared__ int lh[NBP];
    for (int t = threadIdx.x; t < NBP; t += blockDim.x) lh[t] = 0;
    __syncthreads();
    int stride = gridDim.x * blockDim.x;
    for (int e = blockIdx.x * blockDim.x + threadIdx.x; e < NE; e += stride)
        atomicAdd(&lh[dsts[e] >> 7], 1);
    __syncthreads();
    for (int t = threadIdx.x; t < NB; t += blockDim.x) {
        int c = lh[t];
        if (c) atomicAdd(&bcount[t], c);
    }
}

// ---------------------------------------------------------------------------
// Exclusive prefix over bucket counts -> bases + cursors. One block, 1024 thr.
__global__ void bucket_scan(const int* __restrict__ bcount,
                            int* __restrict__ bbase, int* __restrict__ bcursor) {
    __shared__ int sc[NBP];
    int t = threadIdx.x;
    sc[t] = (t < NB) ? bcount[t] : 0;
    __syncthreads();
    for (int s = 1; s < NBP; s <<= 1) {
        int v = (t >= s) ? sc[t - s] : 0;
        __syncthreads();
        sc[t] += v;
        __syncthreads();
    }
    int excl = (t == 0) ? 0 : sc[t - 1];
    if (t < NB) { bbase[t] = excl; bcursor[t] = excl; }
}

// ---------------------------------------------------------------------------
// Counting-sort each CHUNK of edges by coarse bucket in LDS, then flush packed
// ((dst&127)<<17)|src words to per-bucket global runs (coalesced-ish).
__global__ __launch_bounds__(NBP) void bucket_scatter(
        const int* __restrict__ srcs, const int* __restrict__ dsts,
        int* __restrict__ bcursor, unsigned int* __restrict__ pk) {
    __shared__ int lh[NBP];                 // per-chunk bucket counts
    __shared__ int off[NBP];                // exclusive offsets -> cursors
    __shared__ int gb[NBP];                 // global_run_base - local_excl
    __shared__ unsigned int ssrc[CHUNK];
    __shared__ unsigned int sdst[CHUNK];
    int t = threadIdx.x;                    // 1024 threads
    int base = blockIdx.x * CHUNK;
    int n = NE - base; if (n > CHUNK) n = CHUNK;

    lh[t] = 0;
    __syncthreads();
    for (int i = t; i < n; i += NBP)
        atomicAdd(&lh[dsts[base + i] >> 7], 1);
    __syncthreads();
    off[t] = lh[t];
    __syncthreads();
    for (int s = 1; s < NBP; s <<= 1) {     // inclusive scan
        int v = (t >= s) ? off[t - s] : 0;
        __syncthreads();
        off[t] += v;
        __syncthreads();
    }
    int cnt  = lh[t];
    int excl = off[t] - cnt;                // own-index only: no sync needed
    off[t] = excl;                          // becomes the LDS scatter cursor
    if (cnt > 0) gb[t] = atomicAdd(&bcursor[t], cnt) - excl;
    __syncthreads();
    for (int i = t; i < n; i += NBP) {
        int d = dsts[base + i];
        int s = srcs[base + i];
        int p = atomicAdd(&off[d >> 7], 1);
        ssrc[p] = (unsigned int)s;
        sdst[p] = (unsigned int)d;
    }
    __syncthreads();
    for (int p = t; p < n; p += NBP) {
        unsigned int d = sdst[p];
        int b = d >> 7;
        pk[gb[b] + p] = ((d & 127u) << 17) | ssrc[p];
    }
}

// ---------------------------------------------------------------------------
// One block per coarse bucket: exact deg/row_start/dinv for its 128 dsts and
// fully-sorted csr_src flushed coalesced. csr_src may alias pk_in (each block
// reads its own range completely before overwriting it).
__global__ void fine_csr(const unsigned int* __restrict__ pk_in,
                         int* __restrict__ csr_src,
                         const int* __restrict__ bbase, const int* __restrict__ bcount,
                         int* __restrict__ deg, int* __restrict__ row_start,
                         float* __restrict__ dinv) {
    __shared__ int lh[128], off[128];
    __shared__ int sbuf[BCAP];
    int b  = blockIdx.x;
    int t  = threadIdx.x;                   // 256 threads
    int b0 = bbase[b];
    int cnt = bcount[b];
    if (t < 128) lh[t] = 0;
    __syncthreads();
    for (int i = t; i < cnt; i += 256)
        atomicAdd(&lh[pk_in[b0 + i] >> 17], 1);
    __syncthreads();
    if (t < 128) off[t] = lh[t];
    __syncthreads();
    for (int s = 1; s < 128; s <<= 1) {     // inclusive scan over 128
        int v = (t >= s && t < 128) ? off[t - s] : 0;
        __syncthreads();
        if (t < 128) off[t] += v;
        __syncthreads();
    }
    if (t < 128) {
        int c    = lh[t];
        int excl = off[t] - c;
        int dst  = (b << 7) + t;
        if (dst < NN) {
            deg[dst]       = c;
            row_start[dst] = b0 + excl;
            dinv[dst]      = (c > 0) ? rsqrtf((float)c) : 0.0f;
        }
        off[t] = excl;                      // scatter cursor
    }
    __syncthreads();
    for (int i = t; i < cnt; i += 256) {
        unsigned int v = pk_in[b0 + i];
        int p = atomicAdd(&off[v >> 17], 1);
        sbuf[p] = (int)(v & 0x1FFFFu);
    }
    __syncthreads();
    for (int i = t; i < cnt; i += 256)
        csr_src[b0 + i] = sbuf[i];
}

// ---------------------------------------------------------------------------
// Z0 = bf16(X * dinv); also zero-fill row NN (the dummy row) of BOTH buffers.
__global__ void zinit_kernel(const float* __restrict__ X,
                             const float* __restrict__ dinv,
                             unsigned short* __restrict__ Za,
                             unsigned short* __restrict__ Zb) {
    int i = blockIdx.x * blockDim.x + threadIdx.x;   // [0, (NN+1)*DD)
    if (i >= (NN + 1) * DD) return;
    if (i >= NN * DD) {            // dummy zero row, index NN
        Za[i] = 0;
        Zb[i] = 0;
        return;
    }
    Za[i] = f2bf(X[i] * dinv[i >> 4]);
}

// ---------------------------------------------------------------------------
// Fused gather + combine. 16 lanes per node; lane f owns feature f.
// EVERY chunk is a fully-unrolled 16-step chunk: out-of-range lanes gather
// from the dummy zero row (index NN) instead of running a serialized
// dynamic-trip remainder loop. All 16 gathers per chunk stay in flight.
__global__ void gather_kernel(const int* __restrict__ csr_src,
                              const int* __restrict__ row_start,
                              const int* __restrict__ deg,
                              const float* __restrict__ dinv,
                              const float* __restrict__ X,
                              const int* __restrict__ mask,
                              const unsigned short* __restrict__ Zin,
                              unsigned short* __restrict__ Zout,
                              float* __restrict__ Y,
                              int last) {
    int tid  = blockIdx.x * blockDim.x + threadIdx.x;  // NN*16 exactly
    int node = tid >> 4;
    int f    = tid & 15;
    if (node >= NN) return;

    int start = row_start[node];
    int d     = deg[node];

    float acc = 0.0f;
    for (int i = 0; i < d; i += 16) {
        int sv = (i + f < d)
                   ? __builtin_nontemporal_load(&csr_src[start + i + f])
                   : NN;                       // dummy zero row
        #pragma unroll
        for (int j = 0; j < 16; ++j) {
            int s = __shfl(sv, j, 16);
            acc += bf2f(Zin[s * DD + f]);
        }
    }

    float di = dinv[node];
    float x  = __builtin_nontemporal_load(&X[node * DD + f]);
    float v  = GAMMA * acc * di + ALP * x;
    v = fminf(fmaxf(v, -1.0f), 1.0f);
    if (__builtin_nontemporal_load(&mask[node]) != 0) v = x;
    if (last) Y[node * DD + f]    = v;
    else      Zout[node * DD + f] = f2bf(v * di);
}

// ---------------------------------------------------------------------------
extern "C" void kernel_launch(void* const* d_in, const int* in_sizes, int n_in,
                              void* d_out, int out_size, void* d_ws, size_t ws_size,
                              hipStream_t stream) {
    const int*   edge_index = (const int*)d_in[0];   // (2, E) int32
    const float* X          = (const float*)d_in[1]; // (N, 16) f32
    const int*   mask       = (const int*)d_in[2];   // (N,) bool as int32

    const int* srcs = edge_index;        // row 0
    const int* dsts = edge_index + NE;   // row 1

    float* Y = (float*)d_out;            // (N, 16) f32 output

    // workspace layout (~21 MB)
    int*   bcount    = (int*)d_ws;               // NBP
    int*   bbase     = bcount + NBP;             // NBP
    int*   bcursor   = bbase + NBP;              // NBP
    int*   deg       = bcursor + NBP;            // NN
    int*   row_start = deg + NN;                 // NN
    float* dinv      = (float*)(row_start + NN); // NN
    unsigned int* pk = (unsigned int*)(dinv + NN);   // NE (csr_src aliases this)
    unsigned short* Za = (unsigned short*)(pk + NE); // (NN+1)*DD bf16
    unsigned short* Zb = Za + (NN + 1) * DD;         // (NN+1)*DD bf16
    int*   csr_src   = (int*)pk;

    hipMemsetAsync(bcount, 0, NBP * sizeof(int), stream);

    bucket_hist<<<512, 256, 0, stream>>>(dsts, bcount);
    bucket_scan<<<1, NBP, 0, stream>>>(bcount, bbase, bcursor);
    bucket_scatter<<<NCHUNK, NBP, 0, stream>>>(srcs, dsts, bcursor, pk);
    fine_csr<<<NB, 256, 0, stream>>>(pk, csr_src, bbase, bcount, deg, row_start, dinv);
    zinit_kernel<<<((NN + 1) * DD + 255) / 256, 256, 0, stream>>>(X, dinv, Za, Zb);

    // Z ping-pong: Za -> Zb -> Za -> Zb -> Za -> Y(last)
    const unsigned short* zin  = Za;
    unsigned short*       zout = Zb;
    for (int t = 0; t < 5; ++t) {
        int last = (t == 4);
        gather_kernel<<<(NN * 16) / 256, 256, 0, stream>>>(
            csr_src, row_start, deg, dinv, X, mask, zin, zout, Y, last);
        const unsigned short* tmp = zout;
        zout = (unsigned short*)zin;
        zin  = tmp;
    }
}